// Round 7
// baseline (1493.769 us; speedup 1.0000x reference)
//
#include <hip/hip_runtime.h>

#define BB 4
#define NTUP 256
#define CHN 128
#define CINN 1024
#define HH 120
#define WW 160
#define HWSZ (HH*WW)
#define SRCN 256
#define CT 512

typedef __attribute__((ext_vector_type(8))) _Float16 f16x8;
typedef __attribute__((ext_vector_type(4))) float f32x4;

__device__ __forceinline__ unsigned short f2h(float f) {
  _Float16 h = (_Float16)f;
  return __builtin_bit_cast(unsigned short, h);
}
__device__ __forceinline__ float h2f(unsigned short u) {
  _Float16 h = __builtin_bit_cast(_Float16, u);
  return (float)h;
}

// ---------------- stage 0: rel embedding ----------------
__global__ __launch_bounds__(256) void k_hmid(const float* __restrict__ tf,
    const float* __restrict__ w1, const float* __restrict__ b1,
    float* __restrict__ hmid) {
  int bc = blockIdx.x;            // b*128 + c
  int b = bc >> 7, c = bc & 127;
  int n = threadIdx.x;
  const float* wrow = w1 + (size_t)c * CINN;
  const float* xcol = tf + (size_t)b * CINN * NTUP + n;
  float acc = 0.f;
#pragma unroll 4
  for (int k = 0; k < CINN; ++k)
    acc += wrow[k] * xcol[(size_t)k * NTUP];
  acc += b1[c];
  hmid[(size_t)bc * NTUP + n] = fmaxf(acc, 0.f);
}

__global__ __launch_bounds__(256) void k_w2t(const float* __restrict__ w2,
                                             float* __restrict__ w2t) {
  int i = blockIdx.x * 256 + threadIdx.x;
  if (i >= CHN * CHN) return;
  int o = i >> 7, c = i & 127;
  w2t[c * CHN + o] = w2[i];
}

__global__ __launch_bounds__(128) void k_relmap(const float* __restrict__ hmid,
    const float* __restrict__ w2t, const float* __restrict__ b2,
    float* __restrict__ rmT) {
  int n = blockIdx.x, b = blockIdx.y, o = threadIdx.x;
  const float* hc = hmid + (size_t)b * CHN * NTUP + n;
  float acc = 0.f;
#pragma unroll 4
  for (int c = 0; c < CHN; ++c)
    acc += hc[(size_t)c * NTUP] * w2t[c * CHN + o];
  rmT[((size_t)b * SRCN + n) * CHN + o] = acc + b2[o];
}

// ---------------- img -> state (NHWC fp16, chans 0..127 and 256..383) -----
__global__ __launch_bounds__(256) void k_img_init(const float* __restrict__ img,
                                                  unsigned short* __restrict__ S) {
  int xt = blockIdx.x;
  int y  = blockIdx.y;
  int b  = blockIdx.z;
  __shared__ float t[128 * 33];
  int x0 = xt * 32;
  for (int i = threadIdx.x; i < 128 * 32; i += 256) {
    int c = i >> 5, x = i & 31;
    t[c * 33 + x] = img[(((size_t)b * CHN + c) * HH + y) * WW + x0 + x];
  }
  __syncthreads();
  for (int j = threadIdx.x; j < 32 * 128; j += 256) {
    int x = j >> 7, c = j & 127;
    unsigned short v = f2h(t[c * 33 + x]);
    size_t base = ((size_t)b * HWSZ + (size_t)y * WW + x0 + x) * CT;
    S[base + c] = v;
    S[base + 256 + c] = v;
  }
}

// ---------------- scatter: serial over boxes, ABSOLUTE x-parity ownership -
// Each thread owns channel c = t&127 and x parity xo = t>>7 (absolute).
// Cell (x,c) therefore has a single owner across all boxes -> no LDS race.
__global__ __launch_bounds__(256) void k_scatter(const float* __restrict__ rmT,
    const int* __restrict__ bbox, unsigned short* __restrict__ S) {
  int y  = blockIdx.x;
  int b  = blockIdx.y;
  int x0 = blockIdx.z * 80;
  __shared__ float row[80 * 129];
  int t = threadIdx.x;
  int c = t & 127, xo = t >> 7;
  for (int i = t; i < 80 * 128; i += 256) { int x = i >> 7, cc = i & 127; row[x * 129 + cc] = 0.f; }
  __syncthreads();
  const int* bb = bbox + (size_t)b * NTUP * 8;
  for (int j = 0; j < NTUP; ++j) {
    const int* bp = bb + j * 8;
    int sx1 = bp[0] >> 1, sy1 = bp[1] >> 1, sx2 = bp[2] >> 1, sy2 = bp[3] >> 1;
    int ox1 = bp[4] >> 1, oy1 = bp[5] >> 1, ox2 = bp[6] >> 1, oy2 = bp[7] >> 1;
    int sh = sy2 - sy1, sw = sx2 - sx1, oh = oy2 - oy1, ow = ox2 - ox1;
    if (!((sh >= 5) && (sw >= 5) && (oh >= 5) && (ow >= 5))) continue;
    if (y >= sy1 && y < sy2) {
      int a = max(sx1, x0), e = min(sx2, x0 + 80);
      if (a < e) {
        int idx = min((y - sy1) * SRCN / sh, SRCN - 1);
        float col = rmT[((size_t)b * SRCN + idx) * CHN + c];
        int start = a + ((xo - a) & 1);       // absolute parity: x ≡ xo (mod 2)
        for (int x = start; x < e; x += 2) row[(x - x0) * 129 + c] += col;
      }
    }
    if (y >= oy1 && y < oy2) {
      int a = max(ox1, x0), e = min(ox2, x0 + 80);
      if (a < e) {
        int idx = min((y - oy1) * SRCN / oh, SRCN - 1);
        float col = rmT[((size_t)b * SRCN + idx) * CHN + c];
        int start = a + ((xo - a) & 1);
        for (int x = start; x < e; x += 2) row[(x - x0) * 129 + c] += col;
      }
    }
  }
  __syncthreads();
  for (int j2 = t; j2 < 80 * 128; j2 += 256) {
    int x = j2 >> 7, c2 = j2 & 127;
    unsigned short v = f2h(row[x * 129 + c2]);
    size_t base = ((size_t)b * HWSZ + (size_t)y * WW + x0 + x) * CT;
    S[base + 128 + c2] = v;
    S[base + 384 + c2] = v;
  }
}

// ---------------- weight packing: [tap][oc][icp] fp16 ---------------------
__global__ void k_pack(const float* __restrict__ wA, int ICa,
                       const float* __restrict__ wB, int ICb,
                       int OC, unsigned short* __restrict__ dst) {
  int ICP = ICa + ICb;
  int total = 9 * OC * ICP;
  int i = blockIdx.x * 256 + threadIdx.x;
  if (i >= total) return;
  int tap = i / (OC * ICP); int r = i % (OC * ICP);
  int oc = r / ICP; int icp = r % ICP;
  int dy = tap / 3, dx = tap % 3;
  float v;
  if (icp < ICa) v = wA[((size_t)(oc * ICa + icp) * 3 + dy) * 3 + dx];
  else           v = wB[((size_t)(oc * ICb + (icp - ICa)) * 3 + dy) * 3 + dx];
  dst[i] = f2h(v);
}

// ---------------- the MFMA conv engine ------------------------------------
struct ConvGroup {
  const unsigned short* w;       // [9][OCg][ICP]
  const float* biasA;
  const float* biasB;            // nullable
  const unsigned short* res;     // nullable (residual, NHWC Ct_in)
  int ICP, OCg, oc_wbase;
  int c0a, na, c0b;
  int res_c0, out_c0;
  float scale;
  int relu;
};
struct ConvCommon {
  const unsigned short* in; int Ct_in;
  unsigned short* outb; int Ct_out;
  float* outf;                   // non-null -> f32 NCHW output
};
struct ConvParams { ConvCommon c; ConvGroup g[4]; };

__global__ __launch_bounds__(512) void k_conv(ConvParams P) {
  const ConvGroup G = P.g[blockIdx.z];
  const int b  = blockIdx.y;
  const int y0 = blockIdx.x * 2;
  const int t = threadIdx.x;
  const int wave = t >> 6, lane = t & 63;
  const int wm = wave & 1, wn = wave >> 1;
  const int r = wn >> 1;               // output row within tile (0/1)
  const int xbase = (wn & 1) * 80;     // x half
  const int ln = lane & 15, kg = lane >> 4;

  __shared__ unsigned short lds[4 * 162 * 32];   // [row 0..3][xp 0..161][ic 0..31]

  f32x4 acc[4][5];
#pragma unroll
  for (int m = 0; m < 4; ++m)
#pragma unroll
    for (int n = 0; n < 5; ++n) acc[m][n] = (f32x4)(0.f);

  const int nch = G.ICP >> 5;
  for (int k = 0; k < nch; ++k) {
    const int icp0 = k << 5;
    const int cg = (icp0 < G.na) ? (G.c0a + icp0) : (G.c0b + icp0 - G.na);
    __syncthreads();
    if (t < 32) {            // zero x-halo columns (xp = 0 and 161)
      int icg = t & 3, hx = (t >> 2) & 1, rw = t >> 3;
      uint4 z = {0u, 0u, 0u, 0u};
      *(uint4*)&lds[((rw * 162) + (hx ? 161 : 0)) * 32 + icg * 8] = z;
    }
#pragma unroll
    for (int s = 0; s < 5; ++s) {      // 4 rows x 160 x x 32 ic, 16B per thread
      int id = t + (s << 9);
      int icg = id & 3;
      int xx = (id >> 2) % 160;
      int rw = (id >> 2) / 160;
      int ry = y0 - 1 + rw;
      uint4 v = {0u, 0u, 0u, 0u};
      if (ry >= 0 && ry < HH)
        v = *(const uint4*)(P.c.in + ((size_t)b * HWSZ + (size_t)ry * WW + xx) * P.c.Ct_in + cg + icg * 8);
      *(uint4*)&lds[((rw * 162) + xx + 1) * 32 + icg * 8] = v;
    }
    __syncthreads();
#pragma unroll
    for (int dy = 0; dy < 3; ++dy) {
      const int lrow = (r + dy) * 162;
#pragma unroll
      for (int dx = 0; dx < 3; ++dx) {
        const int tap = dy * 3 + dx;
        const unsigned short* wp = G.w +
            ((size_t)(tap * G.OCg + G.oc_wbase + wm * 64 + ln)) * G.ICP + icp0 + kg * 8;
        f16x8 A[4];
#pragma unroll
        for (int m = 0; m < 4; ++m)
          A[m] = *(const f16x8*)(wp + (size_t)m * 16 * G.ICP);
#pragma unroll
        for (int nf = 0; nf < 5; ++nf) {
          const f16x8 Bv = *(const f16x8*)(&lds[(lrow + xbase + nf * 16 + dx + ln) * 32 + kg * 8]);
#pragma unroll
          for (int m = 0; m < 4; ++m)
            acc[m][nf] = __builtin_amdgcn_mfma_f32_16x16x32_f16(A[m], Bv, acc[m][nf], 0, 0, 0);
        }
      }
    }
  }

  // epilogue: bias, scale, residual, relu, store
  const int yy = y0 + r;
#pragma unroll
  for (int m = 0; m < 4; ++m) {
    const int ocl = wm * 64 + m * 16 + (kg << 2);
    const int ocw = G.oc_wbase + ocl;
    float bias[4];
#pragma unroll
    for (int q = 0; q < 4; ++q)
      bias[q] = G.biasA[ocw + q] + (G.biasB ? G.biasB[ocw + q] : 0.f);
#pragma unroll
    for (int nf = 0; nf < 5; ++nf) {
      const int x = xbase + nf * 16 + ln;
      const size_t pix = (size_t)b * HWSZ + (size_t)yy * WW + x;
      float v[4];
#pragma unroll
      for (int q = 0; q < 4; ++q)
        v[q] = (acc[m][nf][q] + bias[q]) * G.scale;
      if (G.res) {
        const unsigned short* rp = G.res + pix * P.c.Ct_in + G.res_c0 + ocw;
        uint2 rv = *(const uint2*)rp;
        v[0] += h2f((unsigned short)(rv.x & 0xffffu));
        v[1] += h2f((unsigned short)(rv.x >> 16));
        v[2] += h2f((unsigned short)(rv.y & 0xffffu));
        v[3] += h2f((unsigned short)(rv.y >> 16));
      }
      if (G.relu) {
#pragma unroll
        for (int q = 0; q < 4; ++q) v[q] = fmaxf(v[q], 0.f);
      }
      if (P.c.outf) {
#pragma unroll
        for (int q = 0; q < 4; ++q)
          P.c.outf[(((size_t)b * CHN + ocw + q) * HH + yy) * WW + x] = v[q];
      } else {
        uint2 pk;
        pk.x = (unsigned)f2h(v[0]) | ((unsigned)f2h(v[1]) << 16);
        pk.y = (unsigned)f2h(v[2]) | ((unsigned)f2h(v[3]) << 16);
        *(uint2*)(P.c.outb + pix * P.c.Ct_out + G.out_c0 + ocw) = pk;
      }
    }
  }
}

// ---------------- host side ----------------------------------------------
extern "C" void kernel_launch(void* const* d_in, const int* in_sizes, int n_in,
                              void* d_out, int out_size, void* d_ws, size_t ws_size,
                              hipStream_t stream) {
  const float* ram     = (const float*)d_in[0];
  const float* tf      = (const float*)d_in[1];
  const float* w1      = (const float*)d_in[2];
  const float* b1      = (const float*)d_in[3];
  const float* w2      = (const float*)d_in[4];
  const float* b2      = (const float*)d_in[5];
  const float* dmc_w   = (const float*)d_in[6];
  const float* dmc_b   = (const float*)d_in[7];
  const float* imc_w01 = (const float*)d_in[8];
  const float* imc_b01 = (const float*)d_in[9];
  const float* imc_w23 = (const float*)d_in[10];
  const float* imc_b23 = (const float*)d_in[11];
  const float* rmc_w01 = (const float*)d_in[12];
  const float* rmc_b01 = (const float*)d_in[13];
  const float* rmc_w23 = (const float*)d_in[14];
  const float* rmc_b23 = (const float*)d_in[15];
  const float* emb_w1  = (const float*)d_in[16];
  const float* emb_b1  = (const float*)d_in[17];
  const float* emb_w2  = (const float*)d_in[18];
  const float* emb_b2  = (const float*)d_in[19];
  const int*   bbox    = (const int*)d_in[20];
  float* out = (float*)d_out;

  char* ws = (char*)d_ws;
  size_t off = 0;
  auto alloc = [&](size_t bytes) -> void* {
    void* p = ws + off;
    off += (bytes + 255) & ~(size_t)255;
    return p;
  };
  unsigned short* SA = (unsigned short*)alloc((size_t)BB * HWSZ * CT * 2);
  unsigned short* SB = (unsigned short*)alloc((size_t)BB * HWSZ * CT * 2);
  unsigned short* T  = (unsigned short*)alloc((size_t)BB * HWSZ * 128 * 2);
  float* hmid = (float*)alloc((size_t)BB * CHN * NTUP * 4);
  float* rmT  = (float*)alloc((size_t)BB * SRCN * CHN * 4);
  float* w2t  = (float*)alloc((size_t)CHN * CHN * 4);
  unsigned short* pw_dm[2], *pw_im[2], *pw_rm[2];
  for (int i = 0; i < 2; ++i) pw_dm[i] = (unsigned short*)alloc((size_t)9 * 256 * 256 * 2);
  for (int i = 0; i < 2; ++i) pw_im[i] = (unsigned short*)alloc((size_t)9 * 128 * 384 * 2);
  for (int i = 0; i < 2; ++i) pw_rm[i] = (unsigned short*)alloc((size_t)9 * 128 * 384 * 2);
  unsigned short* pw_e1 = (unsigned short*)alloc((size_t)9 * 128 * 256 * 2);
  unsigned short* pw_e2 = (unsigned short*)alloc((size_t)9 * 128 * 128 * 2);
  if (off > ws_size) return;

  k_hmid<<<BB * CHN, 256, 0, stream>>>(tf, w1, b1, hmid);
  k_w2t<<<(CHN * CHN + 255) / 256, 256, 0, stream>>>(w2, w2t);
  k_relmap<<<dim3(NTUP, BB), 128, 0, stream>>>(hmid, w2t, b2, rmT);
  k_img_init<<<dim3(5, HH, BB), 256, 0, stream>>>(ram, SA);
  k_scatter<<<dim3(HH, BB, 2), 256, 0, stream>>>(rmT, bbox, SA);

  auto pk = [&](const float* wA, int ICa, const float* wB, int ICb, int OC,
                unsigned short* dst) {
    int total = 9 * OC * (ICa + ICb);
    k_pack<<<(total + 255) / 256, 256, 0, stream>>>(wA, ICa, wB, ICb, OC, dst);
  };
  for (int i = 0; i < 2; ++i) {
    pk(dmc_w + (size_t)i * 256 * 128 * 9, 128, dmc_w + (size_t)(2 + i) * 256 * 128 * 9, 128, 256, pw_dm[i]);
    pk(imc_w01 + (size_t)i * 128 * 256 * 9, 256, imc_w23 + (size_t)i * 128 * 128 * 9, 128, 128, pw_im[i]);
    pk(rmc_w01 + (size_t)i * 128 * 256 * 9, 256, rmc_w23 + (size_t)i * 128 * 128 * 9, 128, 128, pw_rm[i]);
  }
  pk(emb_w1, 256, nullptr, 0, 128, pw_e1);
  pk(emb_w2, 128, nullptr, 0, 128, pw_e2);

  // TriGraph iterations
  for (int i = 0; i < 2; ++i) {
    const unsigned short* Sin = (i == 0) ? SA : SB;
    unsigned short* Sout      = (i == 0) ? SB : SA;
    ConvParams cp;
    cp.c.in = Sin; cp.c.Ct_in = CT; cp.c.outb = Sout; cp.c.Ct_out = CT; cp.c.outf = nullptr;
    for (int h = 0; h < 2; ++h) {
      ConvGroup& g = cp.g[h];
      g.w = pw_dm[i]; g.biasA = dmc_b + (size_t)i * 256; g.biasB = dmc_b + (size_t)(2 + i) * 256;
      g.res = Sin; g.ICP = 256; g.OCg = 256; g.oc_wbase = h * 128;
      g.c0a = 256; g.na = 128; g.c0b = 384;
      g.res_c0 = 0; g.out_c0 = 0; g.scale = 0.5f; g.relu = 1;
    }
    {
      ConvGroup& g = cp.g[2];
      g.w = pw_im[i]; g.biasA = imc_b01 + (size_t)i * 128; g.biasB = imc_b23 + (size_t)i * 128;
      g.res = Sin; g.ICP = 384; g.OCg = 128; g.oc_wbase = 0;
      g.c0a = 0; g.na = 256; g.c0b = 384;
      g.res_c0 = 256; g.out_c0 = 256; g.scale = 0.5f; g.relu = 1;
    }
    {
      ConvGroup& g = cp.g[3];
      g.w = pw_rm[i]; g.biasA = rmc_b01 + (size_t)i * 128; g.biasB = rmc_b23 + (size_t)i * 128;
      g.res = Sin; g.ICP = 384; g.OCg = 128; g.oc_wbase = 0;
      g.c0a = 0; g.na = 256; g.c0b = 256;
      g.res_c0 = 384; g.out_c0 = 384; g.scale = 0.5f; g.relu = 1;
    }
    k_conv<<<dim3(HH / 2, BB, 4), 512, 0, stream>>>(cp);
  }

  { // emb1: T = relu(conv(dep, emb_w1) + b1)
    ConvParams cp;
    cp.c.in = SA; cp.c.Ct_in = CT; cp.c.outb = T; cp.c.Ct_out = 128; cp.c.outf = nullptr;
    ConvGroup& g = cp.g[0];
    g.w = pw_e1; g.biasA = emb_b1; g.biasB = nullptr; g.res = nullptr;
    g.ICP = 256; g.OCg = 128; g.oc_wbase = 0;
    g.c0a = 0; g.na = 256; g.c0b = 0;
    g.res_c0 = -1; g.out_c0 = 0; g.scale = 1.f; g.relu = 1;
    k_conv<<<dim3(HH / 2, BB, 1), 512, 0, stream>>>(cp);
  }
  { // emb2: out(f32, NCHW) = conv(T, emb_w2) + b2
    ConvParams cp;
    cp.c.in = T; cp.c.Ct_in = 128; cp.c.outb = nullptr; cp.c.Ct_out = 0; cp.c.outf = out;
    ConvGroup& g = cp.g[0];
    g.w = pw_e2; g.biasA = emb_b2; g.biasB = nullptr; g.res = nullptr;
    g.ICP = 128; g.OCg = 128; g.oc_wbase = 0;
    g.c0a = 0; g.na = 128; g.c0b = 0;
    g.res_c0 = -1; g.out_c0 = 0; g.scale = 1.f; g.relu = 0;
    k_conv<<<dim3(HH / 2, BB, 1), 512, 0, stream>>>(cp);
  }
}

// Round 8
// 1195.137 us; speedup vs baseline: 1.2499x; 1.2499x over previous
//
#include <hip/hip_runtime.h>

#define BB 4
#define NTUP 256
#define CHN 128
#define CINN 1024
#define HH 120
#define WW 160
#define HWSZ (HH*WW)
#define SRCN 256
#define ROWH (WW*32)           // halfs per (cblk,row): 5120
#define CBS  (HH*ROWH)         // halfs per cblk: 614400

typedef __attribute__((ext_vector_type(8))) _Float16 f16x8;
typedef __attribute__((ext_vector_type(4))) float f32x4;

__device__ __forceinline__ unsigned short f2h(float f) {
  _Float16 h = (_Float16)f;
  return __builtin_bit_cast(unsigned short, h);
}
__device__ __forceinline__ float h2f(unsigned short u) {
  _Float16 h = __builtin_bit_cast(_Float16, u);
  return (float)h;
}

// ---------------- stage 0: rel embedding ----------------
__global__ __launch_bounds__(256) void k_hmid(const float* __restrict__ tf,
    const float* __restrict__ w1, const float* __restrict__ b1,
    float* __restrict__ hmid) {
  int bc = blockIdx.x;            // b*128 + c
  int b = bc >> 7, c = bc & 127;
  int n = threadIdx.x;
  const float* wrow = w1 + (size_t)c * CINN;
  const float* xcol = tf + (size_t)b * CINN * NTUP + n;
  float acc = 0.f;
#pragma unroll 4
  for (int k = 0; k < CINN; ++k)
    acc += wrow[k] * xcol[(size_t)k * NTUP];
  acc += b1[c];
  hmid[(size_t)bc * NTUP + n] = fmaxf(acc, 0.f);
}

__global__ __launch_bounds__(256) void k_w2t(const float* __restrict__ w2,
                                             float* __restrict__ w2t) {
  int i = blockIdx.x * 256 + threadIdx.x;
  if (i >= CHN * CHN) return;
  int o = i >> 7, c = i & 127;
  w2t[c * CHN + o] = w2[i];
}

__global__ __launch_bounds__(128) void k_relmap(const float* __restrict__ hmid,
    const float* __restrict__ w2t, const float* __restrict__ b2,
    float* __restrict__ rmT) {
  int n = blockIdx.x, b = blockIdx.y, o = threadIdx.x;
  const float* hc = hmid + (size_t)b * CHN * NTUP + n;
  float acc = 0.f;
#pragma unroll 4
  for (int c = 0; c < CHN; ++c)
    acc += hc[(size_t)c * NTUP] * w2t[c * CHN + o];
  rmT[((size_t)b * SRCN + n) * CHN + o] = acc + b2[o];
}

// ---------------- img -> state (blocked: S[b][cblk][y][x][32]) ------------
// img chans c -> cblk c/32 (dep) and cblk 8+c/32 (img)
__global__ __launch_bounds__(256) void k_img_init(const float* __restrict__ img,
                                                  unsigned short* __restrict__ S) {
  int xt = blockIdx.x;            // 0..4 (x tile of 32)
  int y  = blockIdx.y;
  int b  = blockIdx.z;
  __shared__ float t[128 * 33];
  int x0 = xt * 32;
  for (int i = threadIdx.x; i < 128 * 32; i += 256) {
    int c = i >> 5, x = i & 31;
    t[c * 33 + x] = img[(((size_t)b * CHN + c) * HH + y) * WW + x0 + x];
  }
  __syncthreads();
  for (int j = threadIdx.x; j < 32 * 128; j += 256) {
    int x = j >> 7, c = j & 127;
    unsigned short v = f2h(t[c * 33 + x]);
    size_t base = (((size_t)b * 16 + (c >> 5)) * HH + y) * ROWH + (size_t)(x0 + x) * 32 + (c & 31);
    S[base] = v;
    S[base + (size_t)8 * CBS] = v;
  }
}

// ---------------- scatter: serial over boxes, ABSOLUTE x-parity ownership -
__global__ __launch_bounds__(256) void k_scatter(const float* __restrict__ rmT,
    const int* __restrict__ bbox, unsigned short* __restrict__ S) {
  int y  = blockIdx.x;
  int b  = blockIdx.y;
  int x0 = blockIdx.z * 80;
  __shared__ float row[80 * 129];
  int t = threadIdx.x;
  int c = t & 127, xo = t >> 7;
  for (int i = t; i < 80 * 128; i += 256) { int x = i >> 7, cc = i & 127; row[x * 129 + cc] = 0.f; }
  __syncthreads();
  const int* bb = bbox + (size_t)b * NTUP * 8;
  for (int j = 0; j < NTUP; ++j) {
    const int* bp = bb + j * 8;
    int sx1 = bp[0] >> 1, sy1 = bp[1] >> 1, sx2 = bp[2] >> 1, sy2 = bp[3] >> 1;
    int ox1 = bp[4] >> 1, oy1 = bp[5] >> 1, ox2 = bp[6] >> 1, oy2 = bp[7] >> 1;
    int sh = sy2 - sy1, sw = sx2 - sx1, oh = oy2 - oy1, ow = ox2 - ox1;
    if (!((sh >= 5) && (sw >= 5) && (oh >= 5) && (ow >= 5))) continue;
    if (y >= sy1 && y < sy2) {
      int a = max(sx1, x0), e = min(sx2, x0 + 80);
      if (a < e) {
        int idx = min((y - sy1) * SRCN / sh, SRCN - 1);
        float col = rmT[((size_t)b * SRCN + idx) * CHN + c];
        int start = a + ((xo - a) & 1);
        for (int x = start; x < e; x += 2) row[(x - x0) * 129 + c] += col;
      }
    }
    if (y >= oy1 && y < oy2) {
      int a = max(ox1, x0), e = min(ox2, x0 + 80);
      if (a < e) {
        int idx = min((y - oy1) * SRCN / oh, SRCN - 1);
        float col = rmT[((size_t)b * SRCN + idx) * CHN + c];
        int start = a + ((xo - a) & 1);
        for (int x = start; x < e; x += 2) row[(x - x0) * 129 + c] += col;
      }
    }
  }
  __syncthreads();
  for (int j2 = t; j2 < 80 * 128; j2 += 256) {
    int x = j2 >> 7, c2 = j2 & 127;
    unsigned short v = f2h(row[x * 129 + c2]);
    size_t base = (((size_t)b * 16 + 4 + (c2 >> 5)) * HH + y) * ROWH + (size_t)(x0 + x) * 32 + (c2 & 31);
    S[base] = v;                       // rel half of dep (cblk 4..7)
    S[base + (size_t)8 * CBS] = v;     // rel (cblk 12..15)
  }
}

// ---------------- weight packing: fragment-major [tap][ocb][icb][l][8] ----
__global__ void k_pack(const float* __restrict__ wA, int ICa,
                       const float* __restrict__ wB, int ICb,
                       int OC, unsigned short* __restrict__ dst) {
  int ICP = ICa + ICb;
  int ICB = ICP >> 5, OCB = OC >> 4;
  int total = 9 * OC * ICP;
  int i = blockIdx.x * 256 + threadIdx.x;
  if (i >= total) return;
  int j = i & 7;
  int l = (i >> 3) & 63;
  int fi = i >> 9;
  int icb = fi % ICB;
  int t2 = fi / ICB;
  int ocb = t2 % OCB;
  int tap = t2 / OCB;
  int oc = ocb * 16 + (l & 15);
  int icp = icb * 32 + (l >> 4) * 8 + j;
  int dy = tap / 3, dx = tap % 3;
  float v;
  if (icp < ICa) v = wA[((size_t)(oc * ICa + icp) * 3 + dy) * 3 + dx];
  else           v = wB[((size_t)(oc * ICb + (icp - ICa)) * 3 + dy) * 3 + dx];
  dst[i] = f2h(v);
}

// ---------------- the MFMA conv engine ------------------------------------
struct ConvGroup {
  const unsigned short* w;       // fragment-major packed
  const float* biasA;
  const float* biasB;            // nullable
  const unsigned short* res;     // nullable (residual, blocked nbin)
  int ICP, OCg, oc_wbase;
  int c0a, na, c0b;
  int res_c0, out_c0;
  float scale;
  int relu;
};
struct ConvCommon {
  const unsigned short* in; int nbin;    // blocked input, nbin cblks
  unsigned short* outb; int nbout;       // blocked output
  float* outf;                           // non-null -> f32 NCHW output
  int nz;                                // groups per y-tile (grid fast dim)
};
struct ConvParams { ConvCommon c; ConvGroup g[4]; };

__global__ __launch_bounds__(512) void k_conv(ConvParams P) {
  const int gid = blockIdx.x;
  const int z = gid % P.c.nz;
  const int rest = gid / P.c.nz;
  const int b = rest & 3;
  const int y0 = (rest >> 2) * 2;
  const ConvGroup G = P.g[z];
  const int t = threadIdx.x;
  const int wave = t >> 6, lane = t & 63;
  const int wm = wave & 1, wn = wave >> 1;
  const int r = wn >> 1;               // output row within tile (0/1)
  const int xbase = (wn & 1) * 80;     // x half
  const int ln = lane & 15, kg = lane >> 4;

  __shared__ unsigned short lds[4 * 162 * 32];   // [row 0..3][xp 0..161][ic 0..31]

  f32x4 acc[4][5];
#pragma unroll
  for (int m = 0; m < 4; ++m)
#pragma unroll
    for (int n = 0; n < 5; ++n) acc[m][n] = (f32x4)(0.f);

  const int nch = G.ICP >> 5;
  const int ICB = G.ICP >> 5;
  const int OCB = G.OCg >> 4;
  for (int k = 0; k < nch; ++k) {
    const int icp0 = k << 5;
    const int cg = (icp0 < G.na) ? (G.c0a + icp0) : (G.c0b + icp0 - G.na);
    const int cblk = cg >> 5;
    const unsigned short* cbase = P.c.in + (((size_t)b * P.c.nbin + cblk) * HH) * ROWH;
    __syncthreads();
    if (t < 32) {            // zero x-halo columns (xp = 0 and 161)
      int icg = t & 3, hx = (t >> 2) & 1, rw = t >> 3;
      uint4 z4 = {0u, 0u, 0u, 0u};
      *(uint4*)&lds[((rw * 162) + (hx ? 161 : 0)) * 32 + icg * 8] = z4;
    }
#pragma unroll
    for (int s = 0; s < 5; ++s) {      // 4 rows x 640 x 16B, contiguous per row
      int u = t + (s << 9);
      int rw = u / 640;
      int rem = u - rw * 640;
      int ry = y0 - 1 + rw;
      uint4 v = {0u, 0u, 0u, 0u};
      if (ry >= 0 && ry < HH)
        v = *(const uint4*)(cbase + (size_t)ry * ROWH + rem * 8);
      *(uint4*)&lds[rw * 5184 + 32 + rem * 8] = v;
    }
    __syncthreads();
#pragma unroll
    for (int dy = 0; dy < 3; ++dy) {
      const int lrow = (r + dy) * 162;
#pragma unroll
      for (int dx = 0; dx < 3; ++dx) {
        const int tap = dy * 3 + dx;
        // fragment-major: contiguous 1KB per wave per fragment
        const size_t frag0 = ((size_t)(tap * OCB + (G.oc_wbase >> 4) + wm * 4) * ICB + k) << 9;
        const unsigned short* wp = G.w + frag0 + lane * 8;
        f16x8 A[4];
#pragma unroll
        for (int m = 0; m < 4; ++m)
          A[m] = *(const f16x8*)(wp + ((size_t)m * ICB << 9));
#pragma unroll
        for (int nf = 0; nf < 5; ++nf) {
          const f16x8 Bv = *(const f16x8*)(&lds[(lrow + xbase + nf * 16 + dx + ln) * 32 + kg * 8]);
#pragma unroll
          for (int m = 0; m < 4; ++m)
            acc[m][nf] = __builtin_amdgcn_mfma_f32_16x16x32_f16(A[m], Bv, acc[m][nf], 0, 0, 0);
        }
      }
    }
  }

  // epilogue: bias, scale, residual, relu, store
  const int yy = y0 + r;
#pragma unroll
  for (int m = 0; m < 4; ++m) {
    const int ocl = wm * 64 + m * 16 + (kg << 2);
    const int ocw = G.oc_wbase + ocl;
    float bias[4];
#pragma unroll
    for (int q = 0; q < 4; ++q)
      bias[q] = G.biasA[ocw + q] + (G.biasB ? G.biasB[ocw + q] : 0.f);
#pragma unroll
    for (int nf = 0; nf < 5; ++nf) {
      const int x = xbase + nf * 16 + ln;
      float v[4];
#pragma unroll
      for (int q = 0; q < 4; ++q)
        v[q] = (acc[m][nf][q] + bias[q]) * G.scale;
      if (G.res) {
        const int rc = G.res_c0 + ocw;
        const unsigned short* rp = G.res +
            (((size_t)b * P.c.nbin + (rc >> 5)) * HH + yy) * ROWH + (size_t)x * 32 + (rc & 31);
        uint2 rv = *(const uint2*)rp;
        v[0] += h2f((unsigned short)(rv.x & 0xffffu));
        v[1] += h2f((unsigned short)(rv.x >> 16));
        v[2] += h2f((unsigned short)(rv.y & 0xffffu));
        v[3] += h2f((unsigned short)(rv.y >> 16));
      }
      if (G.relu) {
#pragma unroll
        for (int q = 0; q < 4; ++q) v[q] = fmaxf(v[q], 0.f);
      }
      if (P.c.outf) {
#pragma unroll
        for (int q = 0; q < 4; ++q)
          P.c.outf[(((size_t)b * CHN + ocw + q) * HH + yy) * WW + x] = v[q];
      } else {
        const int ow = G.out_c0 + ocw;
        uint2 pk;
        pk.x = (unsigned)f2h(v[0]) | ((unsigned)f2h(v[1]) << 16);
        pk.y = (unsigned)f2h(v[2]) | ((unsigned)f2h(v[3]) << 16);
        *(uint2*)(P.c.outb +
            (((size_t)b * P.c.nbout + (ow >> 5)) * HH + yy) * ROWH + (size_t)x * 32 + (ow & 31)) = pk;
      }
    }
  }
}

// ---------------- host side ----------------------------------------------
extern "C" void kernel_launch(void* const* d_in, const int* in_sizes, int n_in,
                              void* d_out, int out_size, void* d_ws, size_t ws_size,
                              hipStream_t stream) {
  const float* ram     = (const float*)d_in[0];
  const float* tf      = (const float*)d_in[1];
  const float* w1      = (const float*)d_in[2];
  const float* b1      = (const float*)d_in[3];
  const float* w2      = (const float*)d_in[4];
  const float* b2      = (const float*)d_in[5];
  const float* dmc_w   = (const float*)d_in[6];
  const float* dmc_b   = (const float*)d_in[7];
  const float* imc_w01 = (const float*)d_in[8];
  const float* imc_b01 = (const float*)d_in[9];
  const float* imc_w23 = (const float*)d_in[10];
  const float* imc_b23 = (const float*)d_in[11];
  const float* rmc_w01 = (const float*)d_in[12];
  const float* rmc_b01 = (const float*)d_in[13];
  const float* rmc_w23 = (const float*)d_in[14];
  const float* rmc_b23 = (const float*)d_in[15];
  const float* emb_w1  = (const float*)d_in[16];
  const float* emb_b1  = (const float*)d_in[17];
  const float* emb_w2  = (const float*)d_in[18];
  const float* emb_b2  = (const float*)d_in[19];
  const int*   bbox    = (const int*)d_in[20];
  float* out = (float*)d_out;

  char* ws = (char*)d_ws;
  size_t off = 0;
  auto alloc = [&](size_t bytes) -> void* {
    void* p = ws + off;
    off += (bytes + 255) & ~(size_t)255;
    return p;
  };
  unsigned short* SA = (unsigned short*)alloc((size_t)BB * 16 * CBS * 2);
  unsigned short* SB = (unsigned short*)alloc((size_t)BB * 16 * CBS * 2);
  unsigned short* T  = (unsigned short*)alloc((size_t)BB * 4 * CBS * 2);
  float* hmid = (float*)alloc((size_t)BB * CHN * NTUP * 4);
  float* rmT  = (float*)alloc((size_t)BB * SRCN * CHN * 4);
  float* w2t  = (float*)alloc((size_t)CHN * CHN * 4);
  unsigned short* pw_dm[2], *pw_im[2], *pw_rm[2];
  for (int i = 0; i < 2; ++i) pw_dm[i] = (unsigned short*)alloc((size_t)9 * 256 * 256 * 2);
  for (int i = 0; i < 2; ++i) pw_im[i] = (unsigned short*)alloc((size_t)9 * 128 * 384 * 2);
  for (int i = 0; i < 2; ++i) pw_rm[i] = (unsigned short*)alloc((size_t)9 * 128 * 384 * 2);
  unsigned short* pw_e1 = (unsigned short*)alloc((size_t)9 * 128 * 256 * 2);
  unsigned short* pw_e2 = (unsigned short*)alloc((size_t)9 * 128 * 128 * 2);
  if (off > ws_size) return;

  k_hmid<<<BB * CHN, 256, 0, stream>>>(tf, w1, b1, hmid);
  k_w2t<<<(CHN * CHN + 255) / 256, 256, 0, stream>>>(w2, w2t);
  k_relmap<<<dim3(NTUP, BB), 128, 0, stream>>>(hmid, w2t, b2, rmT);
  k_img_init<<<dim3(5, HH, BB), 256, 0, stream>>>(ram, SA);
  k_scatter<<<dim3(HH, BB, 2), 256, 0, stream>>>(rmT, bbox, SA);

  auto pk = [&](const float* wA, int ICa, const float* wB, int ICb, int OC,
                unsigned short* dst) {
    int total = 9 * OC * (ICa + ICb);
    k_pack<<<(total + 255) / 256, 256, 0, stream>>>(wA, ICa, wB, ICb, OC, dst);
  };
  for (int i = 0; i < 2; ++i) {
    pk(dmc_w + (size_t)i * 256 * 128 * 9, 128, dmc_w + (size_t)(2 + i) * 256 * 128 * 9, 128, 256, pw_dm[i]);
    pk(imc_w01 + (size_t)i * 128 * 256 * 9, 256, imc_w23 + (size_t)i * 128 * 128 * 9, 128, 128, pw_im[i]);
    pk(rmc_w01 + (size_t)i * 128 * 256 * 9, 256, rmc_w23 + (size_t)i * 128 * 128 * 9, 128, 128, pw_rm[i]);
  }
  pk(emb_w1, 256, nullptr, 0, 128, pw_e1);
  pk(emb_w2, 128, nullptr, 0, 128, pw_e2);

  // TriGraph iterations
  for (int i = 0; i < 2; ++i) {
    const unsigned short* Sin = (i == 0) ? SA : SB;
    unsigned short* Sout      = (i == 0) ? SB : SA;
    ConvParams cp;
    cp.c.in = Sin; cp.c.nbin = 16; cp.c.outb = Sout; cp.c.nbout = 16;
    cp.c.outf = nullptr; cp.c.nz = 4;
    for (int h = 0; h < 2; ++h) {
      ConvGroup& g = cp.g[h];
      g.w = pw_dm[i]; g.biasA = dmc_b + (size_t)i * 256; g.biasB = dmc_b + (size_t)(2 + i) * 256;
      g.res = Sin; g.ICP = 256; g.OCg = 256; g.oc_wbase = h * 128;
      g.c0a = 256; g.na = 128; g.c0b = 384;
      g.res_c0 = 0; g.out_c0 = 0; g.scale = 0.5f; g.relu = 1;
    }
    {
      ConvGroup& g = cp.g[2];
      g.w = pw_im[i]; g.biasA = imc_b01 + (size_t)i * 128; g.biasB = imc_b23 + (size_t)i * 128;
      g.res = Sin; g.ICP = 384; g.OCg = 128; g.oc_wbase = 0;
      g.c0a = 0; g.na = 256; g.c0b = 384;
      g.res_c0 = 256; g.out_c0 = 256; g.scale = 0.5f; g.relu = 1;
    }
    {
      ConvGroup& g = cp.g[3];
      g.w = pw_rm[i]; g.biasA = rmc_b01 + (size_t)i * 128; g.biasB = rmc_b23 + (size_t)i * 128;
      g.res = Sin; g.ICP = 384; g.OCg = 128; g.oc_wbase = 0;
      g.c0a = 0; g.na = 256; g.c0b = 256;
      g.res_c0 = 384; g.out_c0 = 384; g.scale = 0.5f; g.relu = 1;
    }
    k_conv<<<(HH / 2) * BB * 4, 512, 0, stream>>>(cp);
  }

  { // emb1: T = relu(conv(dep, emb_w1) + b1)
    ConvParams cp;
    cp.c.in = SA; cp.c.nbin = 16; cp.c.outb = T; cp.c.nbout = 4;
    cp.c.outf = nullptr; cp.c.nz = 1;
    ConvGroup& g = cp.g[0];
    g.w = pw_e1; g.biasA = emb_b1; g.biasB = nullptr; g.res = nullptr;
    g.ICP = 256; g.OCg = 128; g.oc_wbase = 0;
    g.c0a = 0; g.na = 256; g.c0b = 0;
    g.res_c0 = -1; g.out_c0 = 0; g.scale = 1.f; g.relu = 1;
    k_conv<<<(HH / 2) * BB, 512, 0, stream>>>(cp);
  }
  { // emb2: out(f32, NCHW) = conv(T, emb_w2) + b2
    ConvParams cp;
    cp.c.in = T; cp.c.nbin = 4; cp.c.outb = nullptr; cp.c.nbout = 0;
    cp.c.outf = out; cp.c.nz = 1;
    ConvGroup& g = cp.g[0];
    g.w = pw_e2; g.biasA = emb_b2; g.biasB = nullptr; g.res = nullptr;
    g.ICP = 128; g.OCg = 128; g.oc_wbase = 0;
    g.c0a = 0; g.na = 128; g.c0b = 0;
    g.res_c0 = -1; g.out_c0 = 0; g.scale = 1.f; g.relu = 0;
    k_conv<<<(HH / 2) * BB, 512, 0, stream>>>(cp);
  }
}